// Round 10
// baseline (701.594 us; speedup 1.0000x reference)
//
#include <hip/hip_runtime.h>
#include <hip/hip_bf16.h>

#define MN 50000
#define NE 800000
#define DD 128
#define HH 256
#define PP 512
#define OO 64

typedef unsigned short bf16r;  // raw bf16 bits
using short8 = __attribute__((ext_vector_type(8))) short;
using ushort8 = __attribute__((ext_vector_type(8))) unsigned short;
using f32x4 = __attribute__((ext_vector_type(4))) float;

__device__ __forceinline__ float b2f(bf16r s) {
  unsigned int u = ((unsigned int)s) << 16;
  float f;
  __builtin_memcpy(&f, &u, 4);
  return f;
}
__device__ __forceinline__ bf16r f2b(float f) {
  unsigned int u;
  __builtin_memcpy(&u, &f, 4);
  u += 0x7fffu + ((u >> 16) & 1u);  // RNE
  return (bf16r)(u >> 16);
}
// order-preserving involution bf16 bits <-> signed-int16 sortable key
__device__ __forceinline__ unsigned short keymap(unsigned short u) {
  return u ^ ((u & 0x8000u) ? 0x7FFFu : 0u);
}
__device__ __forceinline__ void stC(float* p, float v) { *p = v; }
__device__ __forceinline__ void stC(bf16r* p, float v) { *p = f2b(v); }

// async global->LDS 16B; LDS dest must be wave-uniform-base + lane*16
__device__ __forceinline__ void async16(void* lds, const void* g) {
  auto l = reinterpret_cast<__attribute__((address_space(3))) char*>(
      reinterpret_cast<uintptr_t>(lds));
  auto gp = reinterpret_cast<const __attribute__((address_space(1))) char*>(
      reinterpret_cast<uintptr_t>(g));
  __builtin_amdgcn_global_load_lds(gp, l, 16, 0, 0);
}

// ---------------- small utility ----------------
__global__ void zero_ints(int* __restrict__ p, int n) {
  int i = blockIdx.x * blockDim.x + threadIdx.x;
  if (i < n) p[i] = 0;
}

// fp32 -> bf16 vectorized convert (4 elems/thread)
__global__ void conv_bf16(const float* __restrict__ in, bf16r* __restrict__ out, int n4) {
  int i = blockIdx.x * 256 + threadIdx.x;
  if (i < n4) {
    float4 v = reinterpret_cast<const float4*>(in)[i];
    ushort4 u;
    u.x = f2b(v.x); u.y = f2b(v.y); u.z = f2b(v.z); u.w = f2b(v.w);
    reinterpret_cast<ushort4*>(out)[i] = u;
  }
}

// all 6 weight transposes in one kernel: B[K][Nc] fp32 -> BT[Nc][K] bf16
__device__ __forceinline__ void tw1(const float* B, bf16r* BT, int i, int K, int Nc) {
  int k = i / Nc, n = i - k * Nc;
  BT[(size_t)n * K + k] = f2b(B[i]);
}
__global__ void transpose_all(const float* __restrict__ b0, const float* __restrict__ b1,
                              const float* __restrict__ b2, const float* __restrict__ b3,
                              const float* __restrict__ b4, const float* __restrict__ b5,
                              bf16r* __restrict__ t0, bf16r* __restrict__ t1,
                              bf16r* __restrict__ t2, bf16r* __restrict__ t3,
                              bf16r* __restrict__ t4, bf16r* __restrict__ t5) {
  int idx = blockIdx.x * 256 + threadIdx.x;
  // cum: 65536, 196608, 327680, 491520, 688128, 737280
  if (idx < 196608) {
    if (idx < 65536) tw1(b0, t0, idx, 128, 512);
    else tw1(b1, t1, idx - 65536, 256, 512);
  } else if (idx < 491520) {
    if (idx < 327680) tw1(b2, t2, idx - 196608, 256, 512);
    else tw1(b3, t3, idx - 327680, 640, 256);
  } else if (idx < 737280) {
    if (idx < 688128) tw1(b4, t4, idx - 491520, 768, 256);
    else tw1(b5, t5, idx - 688128, 768, 64);
  }
}

// ---------------- CSR build (by dst) ----------------
__global__ void count_edges(const int* __restrict__ dst, int* __restrict__ counts) {
  int e = blockIdx.x * blockDim.x + threadIdx.x;
  if (e < NE) atomicAdd(&counts[dst[e]], 1);
}

// 2-level parallel exclusive scan over padded counts (51200 elems, 25 blocks x 2048)
__global__ __launch_bounds__(1024) void scan_local(const int* __restrict__ counts,
                                                   int* __restrict__ row_ptr,
                                                   int* __restrict__ bsum) {
  __shared__ int buf[1024];
  const int b = blockIdx.x, t = threadIdx.x;
  int2 c2 = reinterpret_cast<const int2*>(counts)[b * 1024 + t];
  int tsum = c2.x + c2.y;
  buf[t] = tsum;
  __syncthreads();
  int s = tsum;
  for (int off = 1; off < 1024; off <<= 1) {
    int add = (t >= off) ? buf[t - off] : 0;
    __syncthreads();
    s += add;
    buf[t] = s;
    __syncthreads();
  }
  int excl = s - tsum;
  int2 o;
  o.x = excl;
  o.y = excl + c2.x;
  reinterpret_cast<int2*>(row_ptr)[b * 1024 + t] = o;
  if (t == 1023) bsum[b] = s;
}

__global__ __launch_bounds__(1024) void scan_add(int* __restrict__ row_ptr,
                                                 int* __restrict__ cursor,
                                                 const int* __restrict__ bsum) {
  const int b = blockIdx.x, t = threadIdx.x;
  int off = 0;
  for (int j = 0; j < b; ++j) off += bsum[j];
  int i0 = b * 2048 + 2 * t;
#pragma unroll
  for (int k = 0; k < 2; ++k) {
    int i = i0 + k;
    if (i <= MN) {
      int v = row_ptr[i] + off;
      row_ptr[i] = v;
      if (i < MN) cursor[i] = v;
    }
  }
}

__global__ void scatter_edges(const int* __restrict__ src, const int* __restrict__ dst,
                              int* __restrict__ cursor, int* __restrict__ esrc) {
  int e = blockIdx.x * blockDim.x + threadIdx.x;
  if (e < NE) {
    int d = dst[e];
    int pos = atomicAdd(&cursor[d], 1);
    esrc[pos] = src[e];
  }
}

// ---------------- segment max over chunk-major h ----------------
// h_c layout: [8 chunks][MN nodes][64 feats] keyed bf16 -> one edge-read = one
// 128B line, per-pass gather working set 6.4 MB (~XCD L2). grid (ceil(MN/4), 8),
// chunk slowest. wave = 1 node: 8 edge-groups x 8 lanes x 16B; 16 edges/iter;
// combine via 3 shfl_xor rounds. hN written in normal [node][512] layout.
__global__ __launch_bounds__(256) void seg_max(const bf16r* __restrict__ hc,
                                               const int* __restrict__ row_ptr,
                                               const int* __restrict__ esrc,
                                               bf16r* __restrict__ hN) {
  const int node = blockIdx.x * 4 + (threadIdx.x >> 6);
  if (node >= MN) return;
  const int lane = threadIdx.x & 63;
  const int g = lane >> 3;   // 8 edge groups
  const int sl = lane & 7;   // 8 slots x 8 bf16 = 128B row
  const bf16r* hbase = hc + (size_t)blockIdx.y * MN * 64;
  const int beg = row_ptr[node];
  const int end = row_ptr[node + 1];
  short8 m8;
#pragma unroll
  for (int j = 0; j < 8; ++j) m8[j] = (short)0x807F;  // key(-inf bf16)

  for (int cb = beg; cb < end; cb += 16) {
    int e0 = esrc[min(cb + g, end - 1)];
    int e1 = esrc[min(cb + 8 + g, end - 1)];
    short8 u0 = *reinterpret_cast<const short8*>(hbase + (size_t)e0 * 64 + sl * 8);
    short8 u1 = *reinterpret_cast<const short8*>(hbase + (size_t)e1 * 64 + sl * 8);
    m8 = __builtin_elementwise_max(m8, __builtin_elementwise_max(u0, u1));
  }
  // combine the 8 edge-groups
#pragma unroll
  for (int mask = 8; mask <= 32; mask <<= 1) {
    int4 vi;
    __builtin_memcpy(&vi, &m8, 16);
    int4 ot;
    ot.x = __shfl_xor(vi.x, mask);
    ot.y = __shfl_xor(vi.y, mask);
    ot.z = __shfl_xor(vi.z, mask);
    ot.w = __shfl_xor(vi.w, mask);
    short8 o8;
    __builtin_memcpy(&o8, &ot, 16);
    m8 = __builtin_elementwise_max(m8, o8);
  }
  if (lane < 8) {
    ushort8 o;
    if (beg == end) {
#pragma unroll
      for (int j = 0; j < 8; ++j) o[j] = 0;  // DGL zero-fill
    } else {
#pragma unroll
      for (int j = 0; j < 8; ++j) o[j] = keymap((unsigned short)m8[j]);
    }
    *reinterpret_cast<ushort8*>(hN + (size_t)node * PP + blockIdx.y * 64 + sl * 8) = o;
  }
}

// ---------------- bf16 MFMA GEMM, dbuf staging + XCD-swizzled col-fastest grid ----
// C[M,NC] = A1[M,K1] @ BT^T (+ A2 @ BT[][K1:]^T); optional relu.
// KEYED: write keyed bf16 to CHUNK-MAJOR h_c[col>>6][row][col&63].
template <int BN, int NCB, int WMC, int WNC, bool DUAL, bool RELU, bool KEYED, typename TO>
__global__ __launch_bounds__(256) void gemm_mfma(
    const bf16r* __restrict__ A1, int K1, const bf16r* __restrict__ A2, int K2,
    const bf16r* __restrict__ BT, int Ktot, TO* __restrict__ C, int M, int NC) {
  constexpr int BM = 128, BK = 32;
  constexpr int WM = BM / WMC;
  constexpr int WN = BN / WNC;
  constexpr int FM = WM / 16, FN = WN / 16;
  __shared__ short As[2][BM * BK];
  __shared__ short Bs[2][BN * BK];
  const int tid = threadIdx.x;
  const int lane = tid & 63;
  const int wv = tid >> 6;
  const int wr = wv / WNC, wc = wv % WNC;
  // bijective XCD chunk swizzle: each XCD gets a contiguous wgid range
  const int nwg = gridDim.x;
  const int q = nwg >> 3, r = nwg & 7;
  const int xcd = blockIdx.x & 7, slot = blockIdx.x >> 3;
  const int wgid = (xcd < r ? xcd * (q + 1) : r * (q + 1) + (xcd - r) * q) + slot;
  const int m0 = (wgid / NCB) * BM;
  const int n0 = (wgid % NCB) * BN;

  const int NT1 = K1 / BK;
  const int NT = NT1 + (DUAL ? K2 / BK : 0);

  auto stage = [&](int t, int b) {
    const int o = wv * 1024 + lane * 16;
    // A tile [128][32] bf16 = 8192 B
#pragma unroll
    for (int c = 0; c < 2; ++c) {
      int oo = o + c * 4096;
      int row = oo >> 6, colb = oo & 63;
      const char* g;
      if (!DUAL || t < NT1)
        g = (const char*)A1 + ((size_t)(m0 + row) * K1 + t * BK) * 2 + colb;
      else
        g = (const char*)A2 + ((size_t)(m0 + row) * K2 + (t - NT1) * BK) * 2 + colb;
      async16((char*)&As[b][0] + oo, g);
    }
    // B tile [BN][32] bf16
#pragma unroll
    for (int c = 0; c < BN / 64; ++c) {
      int oo = o + c * 4096;
      int row = oo >> 6, colb = oo & 63;
      const char* g = (const char*)BT + ((size_t)(n0 + row) * Ktot + t * BK) * 2 + colb;
      async16((char*)&Bs[b][0] + oo, g);
    }
  };

  f32x4 acc[FM][FN];
#pragma unroll
  for (int i = 0; i < FM; ++i)
#pragma unroll
    for (int j = 0; j < FN; ++j)
#pragma unroll
      for (int r2 = 0; r2 < 4; ++r2) acc[i][j][r2] = 0.f;

  stage(0, 0);
  __syncthreads();
  for (int t = 0; t < NT; ++t) {
    const int b = t & 1;
    if (t + 1 < NT) stage(t + 1, b ^ 1);
    short8 af[FM], bfv[FN];
#pragma unroll
    for (int i = 0; i < FM; ++i)
      af[i] = *(const short8*)(&As[b][0] + (wr * WM + i * 16 + (lane & 15)) * BK +
                               (lane >> 4) * 8);
#pragma unroll
    for (int j = 0; j < FN; ++j)
      bfv[j] = *(const short8*)(&Bs[b][0] + (wc * WN + j * 16 + (lane & 15)) * BK +
                                (lane >> 4) * 8);
#pragma unroll
    for (int i = 0; i < FM; ++i)
#pragma unroll
      for (int j = 0; j < FN; ++j)
        acc[i][j] =
            __builtin_amdgcn_mfma_f32_16x16x32_bf16(af[i], bfv[j], acc[i][j], 0, 0, 0);
    __syncthreads();  // drains vmcnt(0): next tile staged; all waves done reading b
  }

  // epilogue: C/D layout col=lane&15, row=(lane>>4)*4+r
  const int crow0 = wr * WM + (lane >> 4) * 4;
  const int ccol0 = wc * WN + (lane & 15);
#pragma unroll
  for (int i = 0; i < FM; ++i)
#pragma unroll
    for (int j = 0; j < FN; ++j)
#pragma unroll
      for (int r2 = 0; r2 < 4; ++r2) {
        int row = m0 + crow0 + i * 16 + r2;
        if (row < M) {
          float v = acc[i][j][r2];
          if (RELU) v = fmaxf(v, 0.f);
          int col = n0 + ccol0 + j * 16;
          if (KEYED) {
            // chunk-major h_c[col>>6][row][col&63]
            bf16r* p = (bf16r*)C + ((size_t)(col >> 6) * M + row) * 64 + (col & 63);
            *p = keymap(f2b(v));
          } else {
            stC(&C[(size_t)row * NC + col], v);
          }
        }
      }
}

extern "C" void kernel_launch(void* const* d_in, const int* in_sizes, int n_in,
                              void* d_out, int out_size, void* d_ws, size_t ws_size,
                              hipStream_t stream) {
  const float* x = (const float*)d_in[0];
  const int* src = (const int*)d_in[1];
  const int* dst = (const int*)d_in[2];
  const float* aggW0 = (const float*)d_in[3];
  const float* aggW1 = (const float*)d_in[4];
  const float* aggW2 = (const float*)d_in[5];
  const float* linW0 = (const float*)d_in[6];
  const float* linW1 = (const float*)d_in[7];
  const float* linW2 = (const float*)d_in[8];
  float* out = (float*)d_out;

  char* ws = (char*)d_ws;
  size_t off = 0;
  auto alloc = [&](size_t bytes) {
    void* p = ws + off;
    off = (off + bytes + 255) & ~(size_t)255;
    return p;
  };
  // order matters: GEMM A-staging overreads last-block tail rows into the NEXT buffer
  bf16r* h = (bf16r*)alloc((size_t)MN * PP * 2);      // keyed bf16, CHUNK-MAJOR [8][MN][64]
  bf16r* hN = (bf16r*)alloc((size_t)MN * PP * 2);
  bf16r* act1 = (bf16r*)alloc((size_t)MN * HH * 2);
  bf16r* act2 = (bf16r*)alloc((size_t)MN * HH * 2);
  bf16r* xb = (bf16r*)alloc((size_t)MN * DD * 2);
  bf16r* aggW0T = (bf16r*)alloc(512 * 128 * 2);
  bf16r* aggW1T = (bf16r*)alloc(512 * 256 * 2);
  bf16r* aggW2T = (bf16r*)alloc(512 * 256 * 2);
  bf16r* linW0T = (bf16r*)alloc(640 * 256 * 2);
  bf16r* linW1T = (bf16r*)alloc(768 * 256 * 2);
  bf16r* linW2T = (bf16r*)alloc(768 * 64 * 2);
  int* row_ptr = (int*)alloc(51264 * 4);   // padded for int2 scan
  int* cursor = (int*)alloc(MN * 4);
  int* counts = (int*)alloc(51264 * 4);    // padded, zeroed
  int* bsum = (int*)alloc(32 * 4);
  int* esrc = (int*)alloc(NE * 4);

  // ---- CSR build ----
  zero_ints<<<(51264 + 255) / 256, 256, 0, stream>>>(counts, 51264);
  count_edges<<<(NE + 255) / 256, 256, 0, stream>>>(dst, counts);
  scan_local<<<25, 1024, 0, stream>>>(counts, row_ptr, bsum);
  scan_add<<<25, 1024, 0, stream>>>(row_ptr, cursor, bsum);
  scatter_edges<<<(NE + 255) / 256, 256, 0, stream>>>(src, dst, cursor, esrc);

  // ---- x -> bf16, all weight transposes ----
  conv_bf16<<<((MN * DD / 4) + 255) / 256, 256, 0, stream>>>(x, xb, MN * DD / 4);
  transpose_all<<<(737280 + 255) / 256, 256, 0, stream>>>(
      aggW0, aggW1, aggW2, linW0, linW1, linW2,
      aggW0T, aggW1T, aggW2T, linW0T, linW1T, linW2T);

  const int RB = (MN + 127) / 128;  // 391
  dim3 gagg(RB * 4);                // BN=128, 4 col-blocks, col-fastest 1D
  dim3 glin(RB * 2);                // BN=128, 2 col-blocks
  dim3 gout(RB);                    // BN=64, 1 col-block
  dim3 gseg((MN + 3) / 4, 8);       // 8 feature chunks (chunk-major h), y slowest

  // ---- layer 0 ----
  gemm_mfma<128, 4, 2, 2, false, false, true, bf16r><<<gagg, 256, 0, stream>>>(
      xb, DD, (const bf16r*)nullptr, 0, aggW0T, DD, h, MN, PP);
  seg_max<<<gseg, 256, 0, stream>>>(h, row_ptr, esrc, hN);
  gemm_mfma<128, 2, 2, 2, true, true, false, bf16r><<<glin, 256, 0, stream>>>(
      xb, DD, hN, PP, linW0T, DD + PP, act1, MN, HH);

  // ---- layer 1 ----
  gemm_mfma<128, 4, 2, 2, false, false, true, bf16r><<<gagg, 256, 0, stream>>>(
      act1, HH, (const bf16r*)nullptr, 0, aggW1T, HH, h, MN, PP);
  seg_max<<<gseg, 256, 0, stream>>>(h, row_ptr, esrc, hN);
  gemm_mfma<128, 2, 2, 2, true, true, false, bf16r><<<glin, 256, 0, stream>>>(
      act1, HH, hN, PP, linW1T, HH + PP, act2, MN, HH);

  // ---- layer 2 (output) ----
  gemm_mfma<128, 4, 2, 2, false, false, true, bf16r><<<gagg, 256, 0, stream>>>(
      act2, HH, (const bf16r*)nullptr, 0, aggW2T, HH, h, MN, PP);
  seg_max<<<gseg, 256, 0, stream>>>(h, row_ptr, esrc, hN);
  gemm_mfma<64, 1, 4, 1, true, false, false, float><<<gout, 256, 0, stream>>>(
      act2, HH, hN, PP, linW2T, HH + PP, out, MN, OO);
}

// Round 12
// 637.044 us; speedup vs baseline: 1.1013x; 1.1013x over previous
//
#include <hip/hip_runtime.h>
#include <hip/hip_bf16.h>

#define MN 50000
#define NE 800000
#define DD 128
#define HH 256
#define PP 512
#define OO 64

typedef unsigned short bf16r;  // raw bf16 bits
using short8 = __attribute__((ext_vector_type(8))) short;
using ushort8 = __attribute__((ext_vector_type(8))) unsigned short;
using f32x4 = __attribute__((ext_vector_type(4))) float;

__device__ __forceinline__ float b2f(bf16r s) {
  unsigned int u = ((unsigned int)s) << 16;
  float f;
  __builtin_memcpy(&f, &u, 4);
  return f;
}
__device__ __forceinline__ bf16r f2b(float f) {
  unsigned int u;
  __builtin_memcpy(&u, &f, 4);
  u += 0x7fffu + ((u >> 16) & 1u);  // RNE
  return (bf16r)(u >> 16);
}
// order-preserving involution bf16 bits <-> signed-int16 sortable key
__device__ __forceinline__ unsigned short keymap(unsigned short u) {
  return u ^ ((u & 0x8000u) ? 0x7FFFu : 0u);
}
__device__ __forceinline__ void stC(float* p, float v) { *p = v; }
__device__ __forceinline__ void stC(bf16r* p, float v) { *p = f2b(v); }

// async global->LDS 16B; LDS dest must be wave-uniform-base + lane*16
__device__ __forceinline__ void async16(void* lds, const void* g) {
  auto l = reinterpret_cast<__attribute__((address_space(3))) char*>(
      reinterpret_cast<uintptr_t>(lds));
  auto gp = reinterpret_cast<const __attribute__((address_space(1))) char*>(
      reinterpret_cast<uintptr_t>(g));
  __builtin_amdgcn_global_load_lds(gp, l, 16, 0, 0);
}

// ---------------- small utility ----------------
__global__ void zero_ints(int* __restrict__ p, int n) {
  int i = blockIdx.x * blockDim.x + threadIdx.x;
  if (i < n) p[i] = 0;
}

// fp32 -> bf16 vectorized convert (4 elems/thread)
__global__ void conv_bf16(const float* __restrict__ in, bf16r* __restrict__ out, int n4) {
  int i = blockIdx.x * 256 + threadIdx.x;
  if (i < n4) {
    float4 v = reinterpret_cast<const float4*>(in)[i];
    ushort4 u;
    u.x = f2b(v.x); u.y = f2b(v.y); u.z = f2b(v.z); u.w = f2b(v.w);
    reinterpret_cast<ushort4*>(out)[i] = u;
  }
}

// all 6 weight transposes in one kernel: B[K][Nc] fp32 -> BT[Nc][K] bf16
__device__ __forceinline__ void tw1(const float* B, bf16r* BT, int i, int K, int Nc) {
  int k = i / Nc, n = i - k * Nc;
  BT[(size_t)n * K + k] = f2b(B[i]);
}
__global__ void transpose_all(const float* __restrict__ b0, const float* __restrict__ b1,
                              const float* __restrict__ b2, const float* __restrict__ b3,
                              const float* __restrict__ b4, const float* __restrict__ b5,
                              bf16r* __restrict__ t0, bf16r* __restrict__ t1,
                              bf16r* __restrict__ t2, bf16r* __restrict__ t3,
                              bf16r* __restrict__ t4, bf16r* __restrict__ t5) {
  int idx = blockIdx.x * 256 + threadIdx.x;
  // cum: 65536, 196608, 327680, 491520, 688128, 737280
  if (idx < 196608) {
    if (idx < 65536) tw1(b0, t0, idx, 128, 512);
    else tw1(b1, t1, idx - 65536, 256, 512);
  } else if (idx < 491520) {
    if (idx < 327680) tw1(b2, t2, idx - 196608, 256, 512);
    else tw1(b3, t3, idx - 327680, 640, 256);
  } else if (idx < 737280) {
    if (idx < 688128) tw1(b4, t4, idx - 491520, 768, 256);
    else tw1(b5, t5, idx - 688128, 768, 64);
  }
}

// ---------------- CSR build (by dst) ----------------
__global__ void count_edges(const int* __restrict__ dst, int* __restrict__ counts) {
  int e = blockIdx.x * blockDim.x + threadIdx.x;
  if (e < NE) atomicAdd(&counts[dst[e]], 1);
}

// 2-level parallel exclusive scan over padded counts (51200 elems, 25 blocks x 2048)
__global__ __launch_bounds__(1024) void scan_local(const int* __restrict__ counts,
                                                   int* __restrict__ row_ptr,
                                                   int* __restrict__ bsum) {
  __shared__ int buf[1024];
  const int b = blockIdx.x, t = threadIdx.x;
  int2 c2 = reinterpret_cast<const int2*>(counts)[b * 1024 + t];
  int tsum = c2.x + c2.y;
  buf[t] = tsum;
  __syncthreads();
  int s = tsum;
  for (int off = 1; off < 1024; off <<= 1) {
    int add = (t >= off) ? buf[t - off] : 0;
    __syncthreads();
    s += add;
    buf[t] = s;
    __syncthreads();
  }
  int excl = s - tsum;
  int2 o;
  o.x = excl;
  o.y = excl + c2.x;
  reinterpret_cast<int2*>(row_ptr)[b * 1024 + t] = o;
  if (t == 1023) bsum[b] = s;
}

__global__ __launch_bounds__(1024) void scan_add(int* __restrict__ row_ptr,
                                                 int* __restrict__ cursor,
                                                 const int* __restrict__ bsum) {
  const int b = blockIdx.x, t = threadIdx.x;
  int off = 0;
  for (int j = 0; j < b; ++j) off += bsum[j];
  int i0 = b * 2048 + 2 * t;
#pragma unroll
  for (int k = 0; k < 2; ++k) {
    int i = i0 + k;
    if (i <= MN) {
      int v = row_ptr[i] + off;
      row_ptr[i] = v;
      if (i < MN) cursor[i] = v;
    }
  }
}

__global__ void scatter_edges(const int* __restrict__ src, const int* __restrict__ dst,
                              int* __restrict__ cursor, int* __restrict__ esrc) {
  int e = blockIdx.x * blockDim.x + threadIdx.x;
  if (e < NE) {
    int d = dst[e];
    int pos = atomicAdd(&cursor[d], 1);
    esrc[pos] = src[e];
  }
}

// ---------------- segment max, 4 feature chunks, 4-deep MLP ----------------
// R9-measured-best structure (4 chunks x 256B/edge) with one change: 4 independent
// gather loads in flight per iteration (16 edges/iter). grid (ceil(MN/4), 4),
// chunk slowest. wave = 1 node: 4 edge-groups x 16 lanes x 16B. keyed-i16 packed
// max; cross-group combine via 2 shfl_xor rounds.
__global__ __launch_bounds__(256) void seg_max(const bf16r* __restrict__ h,
                                               const int* __restrict__ row_ptr,
                                               const int* __restrict__ esrc,
                                               bf16r* __restrict__ hN) {
  const int node = blockIdx.x * 4 + (threadIdx.x >> 6);
  if (node >= MN) return;
  const int lane = threadIdx.x & 63;
  const int g = lane >> 4;
  const int sl = lane & 15;
  const int colbase = blockIdx.y * 128 + sl * 8;  // feature offset (8 bf16 = 16B)
  const int beg = row_ptr[node];
  const int end = row_ptr[node + 1];
  short8 m8;
#pragma unroll
  for (int j = 0; j < 8; ++j) m8[j] = (short)0x807F;  // key(-inf bf16)

  for (int cb = beg; cb < end; cb += 16) {
    int e0 = esrc[min(cb + g, end - 1)];
    int e1 = esrc[min(cb + 4 + g, end - 1)];
    int e2 = esrc[min(cb + 8 + g, end - 1)];
    int e3 = esrc[min(cb + 12 + g, end - 1)];
    short8 u0 = *reinterpret_cast<const short8*>(h + ((size_t)e0 << 9) + colbase);
    short8 u1 = *reinterpret_cast<const short8*>(h + ((size_t)e1 << 9) + colbase);
    short8 u2 = *reinterpret_cast<const short8*>(h + ((size_t)e2 << 9) + colbase);
    short8 u3 = *reinterpret_cast<const short8*>(h + ((size_t)e3 << 9) + colbase);
    m8 = __builtin_elementwise_max(m8, __builtin_elementwise_max(
        __builtin_elementwise_max(u0, u1), __builtin_elementwise_max(u2, u3)));
  }
  // combine the 4 lane-groups (each holds max over its edge subset)
#pragma unroll
  for (int mask = 16; mask <= 32; mask <<= 1) {
    int4 vi;
    __builtin_memcpy(&vi, &m8, 16);
    int4 ot;
    ot.x = __shfl_xor(vi.x, mask);
    ot.y = __shfl_xor(vi.y, mask);
    ot.z = __shfl_xor(vi.z, mask);
    ot.w = __shfl_xor(vi.w, mask);
    short8 o8;
    __builtin_memcpy(&o8, &ot, 16);
    m8 = __builtin_elementwise_max(m8, o8);
  }
  if (lane < 16) {
    ushort8 o;
    if (beg == end) {
#pragma unroll
      for (int j = 0; j < 8; ++j) o[j] = 0;  // DGL zero-fill
    } else {
#pragma unroll
      for (int j = 0; j < 8; ++j) o[j] = keymap((unsigned short)m8[j]);
    }
    *reinterpret_cast<ushort8*>(hN + (size_t)node * PP + colbase) = o;
  }
}

// ---------------- bf16 MFMA GEMM, dbuf staging + XCD-swizzled col-fastest grid ----
// C[M,NC] = A1[M,K1] @ BT^T (+ A2 @ BT[][K1:]^T); optional relu.
// 1-D grid, wgid col-fastest (consecutive wgids share the A row-panel);
// bijective XCD-chunk swizzle (m204) puts a row's col-blocks on ONE XCD -> A L2 hits.
template <int BN, int NCB, int WMC, int WNC, bool DUAL, bool RELU, bool KEYED, typename TO>
__global__ __launch_bounds__(256) void gemm_mfma(
    const bf16r* __restrict__ A1, int K1, const bf16r* __restrict__ A2, int K2,
    const bf16r* __restrict__ BT, int Ktot, TO* __restrict__ C, int M, int NC) {
  constexpr int BM = 128, BK = 32;
  constexpr int WM = BM / WMC;
  constexpr int WN = BN / WNC;
  constexpr int FM = WM / 16, FN = WN / 16;
  __shared__ short As[2][BM * BK];
  __shared__ short Bs[2][BN * BK];
  const int tid = threadIdx.x;
  const int lane = tid & 63;
  const int wv = tid >> 6;
  const int wr = wv / WNC, wc = wv % WNC;
  // bijective XCD chunk swizzle: each XCD gets a contiguous wgid range
  const int nwg = gridDim.x;
  const int q = nwg >> 3, r = nwg & 7;
  const int xcd = blockIdx.x & 7, slot = blockIdx.x >> 3;
  const int wgid = (xcd < r ? xcd * (q + 1) : r * (q + 1) + (xcd - r) * q) + slot;
  const int m0 = (wgid / NCB) * BM;
  const int n0 = (wgid % NCB) * BN;

  const int NT1 = K1 / BK;
  const int NT = NT1 + (DUAL ? K2 / BK : 0);

  auto stage = [&](int t, int b) {
    const int o = wv * 1024 + lane * 16;
    // A tile [128][32] bf16 = 8192 B
#pragma unroll
    for (int c = 0; c < 2; ++c) {
      int oo = o + c * 4096;
      int row = oo >> 6, colb = oo & 63;
      const char* g;
      if (!DUAL || t < NT1)
        g = (const char*)A1 + ((size_t)(m0 + row) * K1 + t * BK) * 2 + colb;
      else
        g = (const char*)A2 + ((size_t)(m0 + row) * K2 + (t - NT1) * BK) * 2 + colb;
      async16((char*)&As[b][0] + oo, g);
    }
    // B tile [BN][32] bf16
#pragma unroll
    for (int c = 0; c < BN / 64; ++c) {
      int oo = o + c * 4096;
      int row = oo >> 6, colb = oo & 63;
      const char* g = (const char*)BT + ((size_t)(n0 + row) * Ktot + t * BK) * 2 + colb;
      async16((char*)&Bs[b][0] + oo, g);
    }
  };

  f32x4 acc[FM][FN];
#pragma unroll
  for (int i = 0; i < FM; ++i)
#pragma unroll
    for (int j = 0; j < FN; ++j)
#pragma unroll
      for (int r2 = 0; r2 < 4; ++r2) acc[i][j][r2] = 0.f;

  stage(0, 0);
  __syncthreads();
  for (int t = 0; t < NT; ++t) {
    const int b = t & 1;
    if (t + 1 < NT) stage(t + 1, b ^ 1);
    short8 af[FM], bfv[FN];
#pragma unroll
    for (int i = 0; i < FM; ++i)
      af[i] = *(const short8*)(&As[b][0] + (wr * WM + i * 16 + (lane & 15)) * BK +
                               (lane >> 4) * 8);
#pragma unroll
    for (int j = 0; j < FN; ++j)
      bfv[j] = *(const short8*)(&Bs[b][0] + (wc * WN + j * 16 + (lane & 15)) * BK +
                                (lane >> 4) * 8);
#pragma unroll
    for (int i = 0; i < FM; ++i)
#pragma unroll
      for (int j = 0; j < FN; ++j)
        acc[i][j] =
            __builtin_amdgcn_mfma_f32_16x16x32_bf16(af[i], bfv[j], acc[i][j], 0, 0, 0);
    __syncthreads();  // drains vmcnt(0): next tile staged; all waves done reading b
  }

  // epilogue: C/D layout col=lane&15, row=(lane>>4)*4+r
  const int crow0 = wr * WM + (lane >> 4) * 4;
  const int ccol0 = wc * WN + (lane & 15);
#pragma unroll
  for (int i = 0; i < FM; ++i)
#pragma unroll
    for (int j = 0; j < FN; ++j)
#pragma unroll
      for (int r2 = 0; r2 < 4; ++r2) {
        int row = m0 + crow0 + i * 16 + r2;
        if (row < M) {
          float v = acc[i][j][r2];
          if (RELU) v = fmaxf(v, 0.f);
          TO* p = &C[(size_t)row * NC + n0 + ccol0 + j * 16];
          if (KEYED) {
            *(bf16r*)p = keymap(f2b(v));
          } else {
            stC(p, v);
          }
        }
      }
}

extern "C" void kernel_launch(void* const* d_in, const int* in_sizes, int n_in,
                              void* d_out, int out_size, void* d_ws, size_t ws_size,
                              hipStream_t stream) {
  const float* x = (const float*)d_in[0];
  const int* src = (const int*)d_in[1];
  const int* dst = (const int*)d_in[2];
  const float* aggW0 = (const float*)d_in[3];
  const float* aggW1 = (const float*)d_in[4];
  const float* aggW2 = (const float*)d_in[5];
  const float* linW0 = (const float*)d_in[6];
  const float* linW1 = (const float*)d_in[7];
  const float* linW2 = (const float*)d_in[8];
  float* out = (float*)d_out;

  char* ws = (char*)d_ws;
  size_t off = 0;
  auto alloc = [&](size_t bytes) {
    void* p = ws + off;
    off = (off + bytes + 255) & ~(size_t)255;
    return p;
  };
  // order matters: GEMM A-staging overreads last-block tail rows into the NEXT buffer
  bf16r* h = (bf16r*)alloc((size_t)MN * PP * 2);      // keyed bf16
  bf16r* hN = (bf16r*)alloc((size_t)MN * PP * 2);
  bf16r* act1 = (bf16r*)alloc((size_t)MN * HH * 2);
  bf16r* act2 = (bf16r*)alloc((size_t)MN * HH * 2);
  bf16r* xb = (bf16r*)alloc((size_t)MN * DD * 2);
  bf16r* aggW0T = (bf16r*)alloc(512 * 128 * 2);
  bf16r* aggW1T = (bf16r*)alloc(512 * 256 * 2);
  bf16r* aggW2T = (bf16r*)alloc(512 * 256 * 2);
  bf16r* linW0T = (bf16r*)alloc(640 * 256 * 2);
  bf16r* linW1T = (bf16r*)alloc(768 * 256 * 2);
  bf16r* linW2T = (bf16r*)alloc(768 * 64 * 2);
  int* row_ptr = (int*)alloc(51264 * 4);   // padded for int2 scan
  int* cursor = (int*)alloc(MN * 4);
  int* counts = (int*)alloc(51264 * 4);    // padded, zeroed
  int* bsum = (int*)alloc(32 * 4);
  int* esrc = (int*)alloc(NE * 4);

  // ---- CSR build ----
  zero_ints<<<(51264 + 255) / 256, 256, 0, stream>>>(counts, 51264);
  count_edges<<<(NE + 255) / 256, 256, 0, stream>>>(dst, counts);
  scan_local<<<25, 1024, 0, stream>>>(counts, row_ptr, bsum);
  scan_add<<<25, 1024, 0, stream>>>(row_ptr, cursor, bsum);
  scatter_edges<<<(NE + 255) / 256, 256, 0, stream>>>(src, dst, cursor, esrc);

  // ---- x -> bf16, all weight transposes ----
  conv_bf16<<<((MN * DD / 4) + 255) / 256, 256, 0, stream>>>(x, xb, MN * DD / 4);
  transpose_all<<<(737280 + 255) / 256, 256, 0, stream>>>(
      aggW0, aggW1, aggW2, linW0, linW1, linW2,
      aggW0T, aggW1T, aggW2T, linW0T, linW1T, linW2T);

  const int RB = (MN + 127) / 128;  // 391
  dim3 gagg(RB * 4);                // BN=128, 4 col-blocks, col-fastest 1D
  dim3 glin(RB * 2);                // BN=128, 2 col-blocks
  dim3 gout(RB);                    // BN=64, 1 col-block
  dim3 gseg((MN + 3) / 4, 4);       // 4 feature chunks, y slowest

  // ---- layer 0 ----
  gemm_mfma<128, 4, 2, 2, false, false, true, bf16r><<<gagg, 256, 0, stream>>>(
      xb, DD, (const bf16r*)nullptr, 0, aggW0T, DD, h, MN, PP);
  seg_max<<<gseg, 256, 0, stream>>>(h, row_ptr, esrc, hN);
  gemm_mfma<128, 2, 2, 2, true, true, false, bf16r><<<glin, 256, 0, stream>>>(
      xb, DD, hN, PP, linW0T, DD + PP, act1, MN, HH);

  // ---- layer 1 ----
  gemm_mfma<128, 4, 2, 2, false, false, true, bf16r><<<gagg, 256, 0, stream>>>(
      act1, HH, (const bf16r*)nullptr, 0, aggW1T, HH, h, MN, PP);
  seg_max<<<gseg, 256, 0, stream>>>(h, row_ptr, esrc, hN);
  gemm_mfma<128, 2, 2, 2, true, true, false, bf16r><<<glin, 256, 0, stream>>>(
      act1, HH, hN, PP, linW1T, HH + PP, act2, MN, HH);

  // ---- layer 2 (output) ----
  gemm_mfma<128, 4, 2, 2, false, false, true, bf16r><<<gagg, 256, 0, stream>>>(
      act2, HH, (const bf16r*)nullptr, 0, aggW2T, HH, h, MN, PP);
  seg_max<<<gseg, 256, 0, stream>>>(h, row_ptr, esrc, hN);
  gemm_mfma<64, 1, 4, 1, true, false, false, float><<<gout, 256, 0, stream>>>(
      act2, HH, hN, PP, linW2T, HH + PP, out, MN, OO);
}

// Round 13
// 613.633 us; speedup vs baseline: 1.1433x; 1.0382x over previous
//
#include <hip/hip_runtime.h>
#include <hip/hip_bf16.h>

#define MN 50000
#define NE 800000
#define DD 128
#define HH 256
#define PP 512
#define OO 64

typedef unsigned short bf16r;  // raw bf16 bits
using short8 = __attribute__((ext_vector_type(8))) short;
using ushort8 = __attribute__((ext_vector_type(8))) unsigned short;
using f32x4 = __attribute__((ext_vector_type(4))) float;

__device__ __forceinline__ float b2f(bf16r s) {
  unsigned int u = ((unsigned int)s) << 16;
  float f;
  __builtin_memcpy(&f, &u, 4);
  return f;
}
__device__ __forceinline__ bf16r f2b(float f) {
  unsigned int u;
  __builtin_memcpy(&u, &f, 4);
  u += 0x7fffu + ((u >> 16) & 1u);  // RNE
  return (bf16r)(u >> 16);
}
// order-preserving involution bf16 bits <-> signed-int16 sortable key
__device__ __forceinline__ unsigned short keymap(unsigned short u) {
  return u ^ ((u & 0x8000u) ? 0x7FFFu : 0u);
}
__device__ __forceinline__ void stC(float* p, float v) { *p = v; }
__device__ __forceinline__ void stC(bf16r* p, float v) { *p = f2b(v); }

// async global->LDS 16B; LDS dest must be wave-uniform-base + lane*16
__device__ __forceinline__ void async16(void* lds, const void* g) {
  auto l = reinterpret_cast<__attribute__((address_space(3))) char*>(
      reinterpret_cast<uintptr_t>(lds));
  auto gp = reinterpret_cast<const __attribute__((address_space(1))) char*>(
      reinterpret_cast<uintptr_t>(g));
  __builtin_amdgcn_global_load_lds(gp, l, 16, 0, 0);
}

// ---------------- small utility ----------------
__global__ void zero_ints(int* __restrict__ p, int n) {
  int i = blockIdx.x * blockDim.x + threadIdx.x;
  if (i < n) p[i] = 0;
}

// fp32 -> bf16 vectorized convert (4 elems/thread)
__global__ void conv_bf16(const float* __restrict__ in, bf16r* __restrict__ out, int n4) {
  int i = blockIdx.x * 256 + threadIdx.x;
  if (i < n4) {
    float4 v = reinterpret_cast<const float4*>(in)[i];
    ushort4 u;
    u.x = f2b(v.x); u.y = f2b(v.y); u.z = f2b(v.z); u.w = f2b(v.w);
    reinterpret_cast<ushort4*>(out)[i] = u;
  }
}

// all 6 weight transposes in one kernel: B[K][Nc] fp32 -> BT[Nc][K] bf16
__device__ __forceinline__ void tw1(const float* B, bf16r* BT, int i, int K, int Nc) {
  int k = i / Nc, n = i - k * Nc;
  BT[(size_t)n * K + k] = f2b(B[i]);
}
__global__ void transpose_all(const float* __restrict__ b0, const float* __restrict__ b1,
                              const float* __restrict__ b2, const float* __restrict__ b3,
                              const float* __restrict__ b4, const float* __restrict__ b5,
                              bf16r* __restrict__ t0, bf16r* __restrict__ t1,
                              bf16r* __restrict__ t2, bf16r* __restrict__ t3,
                              bf16r* __restrict__ t4, bf16r* __restrict__ t5) {
  int idx = blockIdx.x * 256 + threadIdx.x;
  // cum: 65536, 196608, 327680, 491520, 688128, 737280
  if (idx < 196608) {
    if (idx < 65536) tw1(b0, t0, idx, 128, 512);
    else tw1(b1, t1, idx - 65536, 256, 512);
  } else if (idx < 491520) {
    if (idx < 327680) tw1(b2, t2, idx - 196608, 256, 512);
    else tw1(b3, t3, idx - 327680, 640, 256);
  } else if (idx < 737280) {
    if (idx < 688128) tw1(b4, t4, idx - 491520, 768, 256);
    else tw1(b5, t5, idx - 688128, 768, 64);
  }
}

// ---------------- CSR build (by dst) ----------------
__global__ void count_edges(const int* __restrict__ dst, int* __restrict__ counts) {
  int e = blockIdx.x * blockDim.x + threadIdx.x;
  if (e < NE) atomicAdd(&counts[dst[e]], 1);
}

// 2-level parallel exclusive scan over padded counts (51200 elems, 25 blocks x 2048)
__global__ __launch_bounds__(1024) void scan_local(const int* __restrict__ counts,
                                                   int* __restrict__ row_ptr,
                                                   int* __restrict__ bsum) {
  __shared__ int buf[1024];
  const int b = blockIdx.x, t = threadIdx.x;
  int2 c2 = reinterpret_cast<const int2*>(counts)[b * 1024 + t];
  int tsum = c2.x + c2.y;
  buf[t] = tsum;
  __syncthreads();
  int s = tsum;
  for (int off = 1; off < 1024; off <<= 1) {
    int add = (t >= off) ? buf[t - off] : 0;
    __syncthreads();
    s += add;
    buf[t] = s;
    __syncthreads();
  }
  int excl = s - tsum;
  int2 o;
  o.x = excl;
  o.y = excl + c2.x;
  reinterpret_cast<int2*>(row_ptr)[b * 1024 + t] = o;
  if (t == 1023) bsum[b] = s;
}

__global__ __launch_bounds__(1024) void scan_add(int* __restrict__ row_ptr,
                                                 int* __restrict__ cursor,
                                                 const int* __restrict__ bsum) {
  const int b = blockIdx.x, t = threadIdx.x;
  int off = 0;
  for (int j = 0; j < b; ++j) off += bsum[j];
  int i0 = b * 2048 + 2 * t;
#pragma unroll
  for (int k = 0; k < 2; ++k) {
    int i = i0 + k;
    if (i <= MN) {
      int v = row_ptr[i] + off;
      row_ptr[i] = v;
      if (i < MN) cursor[i] = v;
    }
  }
}

__global__ void scatter_edges(const int* __restrict__ src, const int* __restrict__ dst,
                              int* __restrict__ cursor, int* __restrict__ esrc) {
  int e = blockIdx.x * blockDim.x + threadIdx.x;
  if (e < NE) {
    int d = dst[e];
    int pos = atomicAdd(&cursor[d], 1);
    esrc[pos] = src[e];
  }
}

// ---------------- segment max, 4 feature chunks, 4-deep MLP (R12: 93.7us) -------
__global__ __launch_bounds__(256) void seg_max(const bf16r* __restrict__ h,
                                               const int* __restrict__ row_ptr,
                                               const int* __restrict__ esrc,
                                               bf16r* __restrict__ hN) {
  const int node = blockIdx.x * 4 + (threadIdx.x >> 6);
  if (node >= MN) return;
  const int lane = threadIdx.x & 63;
  const int g = lane >> 4;
  const int sl = lane & 15;
  const int colbase = blockIdx.y * 128 + sl * 8;  // feature offset (8 bf16 = 16B)
  const int beg = row_ptr[node];
  const int end = row_ptr[node + 1];
  short8 m8;
#pragma unroll
  for (int j = 0; j < 8; ++j) m8[j] = (short)0x807F;  // key(-inf bf16)

  for (int cb = beg; cb < end; cb += 16) {
    int e0 = esrc[min(cb + g, end - 1)];
    int e1 = esrc[min(cb + 4 + g, end - 1)];
    int e2 = esrc[min(cb + 8 + g, end - 1)];
    int e3 = esrc[min(cb + 12 + g, end - 1)];
    short8 u0 = *reinterpret_cast<const short8*>(h + ((size_t)e0 << 9) + colbase);
    short8 u1 = *reinterpret_cast<const short8*>(h + ((size_t)e1 << 9) + colbase);
    short8 u2 = *reinterpret_cast<const short8*>(h + ((size_t)e2 << 9) + colbase);
    short8 u3 = *reinterpret_cast<const short8*>(h + ((size_t)e3 << 9) + colbase);
    m8 = __builtin_elementwise_max(m8, __builtin_elementwise_max(
        __builtin_elementwise_max(u0, u1), __builtin_elementwise_max(u2, u3)));
  }
  // combine the 4 lane-groups (each holds max over its edge subset)
#pragma unroll
  for (int mask = 16; mask <= 32; mask <<= 1) {
    int4 vi;
    __builtin_memcpy(&vi, &m8, 16);
    int4 ot;
    ot.x = __shfl_xor(vi.x, mask);
    ot.y = __shfl_xor(vi.y, mask);
    ot.z = __shfl_xor(vi.z, mask);
    ot.w = __shfl_xor(vi.w, mask);
    short8 o8;
    __builtin_memcpy(&o8, &ot, 16);
    m8 = __builtin_elementwise_max(m8, o8);
  }
  if (lane < 16) {
    ushort8 o;
    if (beg == end) {
#pragma unroll
      for (int j = 0; j < 8; ++j) o[j] = 0;  // DGL zero-fill
    } else {
#pragma unroll
      for (int j = 0; j < 8; ++j) o[j] = keymap((unsigned short)m8[j]);
    }
    *reinterpret_cast<ushort8*>(hN + (size_t)node * PP + colbase) = o;
  }
}

// ---------------- bf16 MFMA GEMM, dbuf staging + XCD-swizzled col-fastest grid ----
// C[M,NC] = A1[M,K1] @ BT^T (+ A2 @ BT[][K1:]^T); optional relu.
// T threads (T/64 waves = WMC x WNC), BM x BN tile, BK=32, double-buffered
// global_load_lds staging, one barrier per K-tile.
template <int T, int BM, int BN, int NCB, int WMC, int WNC, bool DUAL, bool RELU,
          bool KEYED, typename TO>
__global__ __launch_bounds__(T) void gemm_mfma(
    const bf16r* __restrict__ A1, int K1, const bf16r* __restrict__ A2, int K2,
    const bf16r* __restrict__ BT, int Ktot, TO* __restrict__ C, int M, int NC) {
  constexpr int BK = 32;
  constexpr int WM = BM / WMC;
  constexpr int WN = BN / WNC;
  constexpr int FM = WM / 16, FN = WN / 16;
  constexpr int ACH = (BM * 64) / (T * 16);  // A staging shots
  constexpr int BCH = (BN * 64) / (T * 16);  // B staging shots
  __shared__ short As[2][BM * BK];
  __shared__ short Bs[2][BN * BK];
  const int tid = threadIdx.x;
  const int lane = tid & 63;
  const int wv = tid >> 6;
  const int wr = wv / WNC, wc = wv % WNC;
  // bijective XCD chunk swizzle: each XCD gets a contiguous wgid range
  const int nwg = gridDim.x;
  const int q = nwg >> 3, r = nwg & 7;
  const int xcd = blockIdx.x & 7, slot = blockIdx.x >> 3;
  const int wgid = (xcd < r ? xcd * (q + 1) : r * (q + 1) + (xcd - r) * q) + slot;
  const int m0 = (wgid / NCB) * BM;
  const int n0 = (wgid % NCB) * BN;

  const int NT1 = K1 / BK;
  const int NT = NT1 + (DUAL ? K2 / BK : 0);

  auto stage = [&](int t, int b) {
    const int o = tid * 16;
#pragma unroll
    for (int c = 0; c < ACH; ++c) {
      int oo = o + c * (T * 16);
      int row = oo >> 6, colb = oo & 63;
      const char* g;
      if (!DUAL || t < NT1)
        g = (const char*)A1 + ((size_t)(m0 + row) * K1 + t * BK) * 2 + colb;
      else
        g = (const char*)A2 + ((size_t)(m0 + row) * K2 + (t - NT1) * BK) * 2 + colb;
      async16((char*)&As[b][0] + oo, g);
    }
#pragma unroll
    for (int c = 0; c < BCH; ++c) {
      int oo = o + c * (T * 16);
      int row = oo >> 6, colb = oo & 63;
      const char* g = (const char*)BT + ((size_t)(n0 + row) * Ktot + t * BK) * 2 + colb;
      async16((char*)&Bs[b][0] + oo, g);
    }
  };

  f32x4 acc[FM][FN];
#pragma unroll
  for (int i = 0; i < FM; ++i)
#pragma unroll
    for (int j = 0; j < FN; ++j)
#pragma unroll
      for (int r2 = 0; r2 < 4; ++r2) acc[i][j][r2] = 0.f;

  stage(0, 0);
  __syncthreads();
  for (int t = 0; t < NT; ++t) {
    const int b = t & 1;
    if (t + 1 < NT) stage(t + 1, b ^ 1);
    short8 af[FM], bfv[FN];
#pragma unroll
    for (int i = 0; i < FM; ++i)
      af[i] = *(const short8*)(&As[b][0] + (wr * WM + i * 16 + (lane & 15)) * BK +
                               (lane >> 4) * 8);
#pragma unroll
    for (int j = 0; j < FN; ++j)
      bfv[j] = *(const short8*)(&Bs[b][0] + (wc * WN + j * 16 + (lane & 15)) * BK +
                                (lane >> 4) * 8);
#pragma unroll
    for (int i = 0; i < FM; ++i)
#pragma unroll
      for (int j = 0; j < FN; ++j)
        acc[i][j] =
            __builtin_amdgcn_mfma_f32_16x16x32_bf16(af[i], bfv[j], acc[i][j], 0, 0, 0);
    __syncthreads();  // drains vmcnt(0): next tile staged; all waves done reading b
  }

  // epilogue: C/D layout col=lane&15, row=(lane>>4)*4+r
  const int crow0 = wr * WM + (lane >> 4) * 4;
  const int ccol0 = wc * WN + (lane & 15);
#pragma unroll
  for (int i = 0; i < FM; ++i)
#pragma unroll
    for (int j = 0; j < FN; ++j)
#pragma unroll
      for (int r2 = 0; r2 < 4; ++r2) {
        int row = m0 + crow0 + i * 16 + r2;
        if (row < M) {
          float v = acc[i][j][r2];
          if (RELU) v = fmaxf(v, 0.f);
          TO* p = &C[(size_t)row * NC + n0 + ccol0 + j * 16];
          if (KEYED) {
            *(bf16r*)p = keymap(f2b(v));
          } else {
            stC(p, v);
          }
        }
      }
}

extern "C" void kernel_launch(void* const* d_in, const int* in_sizes, int n_in,
                              void* d_out, int out_size, void* d_ws, size_t ws_size,
                              hipStream_t stream) {
  const float* x = (const float*)d_in[0];
  const int* src = (const int*)d_in[1];
  const int* dst = (const int*)d_in[2];
  const float* aggW0 = (const float*)d_in[3];
  const float* aggW1 = (const float*)d_in[4];
  const float* aggW2 = (const float*)d_in[5];
  const float* linW0 = (const float*)d_in[6];
  const float* linW1 = (const float*)d_in[7];
  const float* linW2 = (const float*)d_in[8];
  float* out = (float*)d_out;

  char* ws = (char*)d_ws;
  size_t off = 0;
  auto alloc = [&](size_t bytes) {
    void* p = ws + off;
    off = (off + bytes + 255) & ~(size_t)255;
    return p;
  };
  // order matters: GEMM A-staging overreads last-block tail rows into the NEXT buffer
  bf16r* h = (bf16r*)alloc((size_t)MN * PP * 2);      // keyed bf16
  bf16r* hN = (bf16r*)alloc((size_t)MN * PP * 2);
  bf16r* act1 = (bf16r*)alloc((size_t)MN * HH * 2);
  bf16r* act2 = (bf16r*)alloc((size_t)MN * HH * 2);
  bf16r* xb = (bf16r*)alloc((size_t)MN * DD * 2);
  bf16r* aggW0T = (bf16r*)alloc(512 * 128 * 2);
  bf16r* aggW1T = (bf16r*)alloc(512 * 256 * 2);
  bf16r* aggW2T = (bf16r*)alloc(512 * 256 * 2);
  bf16r* linW0T = (bf16r*)alloc(640 * 256 * 2);
  bf16r* linW1T = (bf16r*)alloc(768 * 256 * 2);
  bf16r* linW2T = (bf16r*)alloc(768 * 64 * 2);
  int* row_ptr = (int*)alloc(51264 * 4);   // padded for int2 scan
  int* cursor = (int*)alloc(MN * 4);
  int* counts = (int*)alloc(51264 * 4);    // padded, zeroed
  int* bsum = (int*)alloc(32 * 4);
  int* esrc = (int*)alloc(NE * 4);

  // ---- CSR build ----
  zero_ints<<<(51264 + 255) / 256, 256, 0, stream>>>(counts, 51264);
  count_edges<<<(NE + 255) / 256, 256, 0, stream>>>(dst, counts);
  scan_local<<<25, 1024, 0, stream>>>(counts, row_ptr, bsum);
  scan_add<<<25, 1024, 0, stream>>>(row_ptr, cursor, bsum);
  scatter_edges<<<(NE + 255) / 256, 256, 0, stream>>>(src, dst, cursor, esrc);

  // ---- x -> bf16, all weight transposes ----
  conv_bf16<<<((MN * DD / 4) + 255) / 256, 256, 0, stream>>>(x, xb, MN * DD / 4);
  transpose_all<<<(737280 + 255) / 256, 256, 0, stream>>>(
      aggW0, aggW1, aggW2, linW0, linW1, linW2,
      aggW0T, aggW1T, aggW2T, linW0T, linW1T, linW2T);

  const int RB256 = (MN + 255) / 256;  // 196
  const int RB128 = (MN + 127) / 128;  // 391
  dim3 gagg(RB256 * 4);                // BM=256, BN=128, 4 col-blocks
  dim3 glin(RB256 * 2);                // BM=256, BN=128, 2 col-blocks
  dim3 gout(RB128);                    // BM=128, BN=64
  dim3 gseg((MN + 3) / 4, 4);          // 4 feature chunks, y slowest

  // ---- layer 0 ----
  gemm_mfma<512, 256, 128, 4, 4, 2, false, false, true, bf16r><<<gagg, 512, 0, stream>>>(
      xb, DD, (const bf16r*)nullptr, 0, aggW0T, DD, h, MN, PP);
  seg_max<<<gseg, 256, 0, stream>>>(h, row_ptr, esrc, hN);
  gemm_mfma<512, 256, 128, 2, 4, 2, true, true, false, bf16r><<<glin, 512, 0, stream>>>(
      xb, DD, hN, PP, linW0T, DD + PP, act1, MN, HH);

  // ---- layer 1 ----
  gemm_mfma<512, 256, 128, 4, 4, 2, false, false, true, bf16r><<<gagg, 512, 0, stream>>>(
      act1, HH, (const bf16r*)nullptr, 0, aggW1T, HH, h, MN, PP);
  seg_max<<<gseg, 256, 0, stream>>>(h, row_ptr, esrc, hN);
  gemm_mfma<512, 256, 128, 2, 4, 2, true, true, false, bf16r><<<glin, 512, 0, stream>>>(
      act1, HH, hN, PP, linW1T, HH + PP, act2, MN, HH);

  // ---- layer 2 (output) ----
  gemm_mfma<512, 256, 128, 4, 4, 2, false, false, true, bf16r><<<gagg, 512, 0, stream>>>(
      act2, HH, (const bf16r*)nullptr, 0, aggW2T, HH, h, MN, PP);
  seg_max<<<gseg, 256, 0, stream>>>(h, row_ptr, esrc, hN);
  gemm_mfma<256, 128, 64, 1, 4, 1, true, false, false, float><<<gout, 256, 0, stream>>>(
      act2, HH, hN, PP, linW2T, HH + PP, out, MN, OO);
}

// Round 14
// 607.341 us; speedup vs baseline: 1.1552x; 1.0104x over previous
//
#include <hip/hip_runtime.h>
#include <hip/hip_bf16.h>

#define MN 50000
#define NE 800000
#define DD 128
#define HH 256
#define PP 512
#define OO 64

typedef unsigned short bf16r;  // raw bf16 bits
using short8 = __attribute__((ext_vector_type(8))) short;
using ushort8 = __attribute__((ext_vector_type(8))) unsigned short;
using f32x4 = __attribute__((ext_vector_type(4))) float;

__device__ __forceinline__ float b2f(bf16r s) {
  unsigned int u = ((unsigned int)s) << 16;
  float f;
  __builtin_memcpy(&f, &u, 4);
  return f;
}
__device__ __forceinline__ bf16r f2b(float f) {
  unsigned int u;
  __builtin_memcpy(&u, &f, 4);
  u += 0x7fffu + ((u >> 16) & 1u);  // RNE
  return (bf16r)(u >> 16);
}
// order-preserving involution bf16 bits <-> signed-int16 sortable key
__device__ __forceinline__ unsigned short keymap(unsigned short u) {
  return u ^ ((u & 0x8000u) ? 0x7FFFu : 0u);
}
__device__ __forceinline__ void stC(float* p, float v) { *p = v; }
__device__ __forceinline__ void stC(bf16r* p, float v) { *p = f2b(v); }

// async global->LDS 16B; LDS dest must be wave-uniform-base + lane*16
__device__ __forceinline__ void async16(void* lds, const void* g) {
  auto l = reinterpret_cast<__attribute__((address_space(3))) char*>(
      reinterpret_cast<uintptr_t>(lds));
  auto gp = reinterpret_cast<const __attribute__((address_space(1))) char*>(
      reinterpret_cast<uintptr_t>(g));
  __builtin_amdgcn_global_load_lds(gp, l, 16, 0, 0);
}

// ---------------- small utility ----------------
__global__ void zero_ints(int* __restrict__ p, int n) {
  int i = blockIdx.x * blockDim.x + threadIdx.x;
  if (i < n) p[i] = 0;
}

// fp32 -> bf16 vectorized convert (4 elems/thread)
__global__ void conv_bf16(const float* __restrict__ in, bf16r* __restrict__ out, int n4) {
  int i = blockIdx.x * 256 + threadIdx.x;
  if (i < n4) {
    float4 v = reinterpret_cast<const float4*>(in)[i];
    ushort4 u;
    u.x = f2b(v.x); u.y = f2b(v.y); u.z = f2b(v.z); u.w = f2b(v.w);
    reinterpret_cast<ushort4*>(out)[i] = u;
  }
}

// all 6 weight transposes in one kernel: B[K][Nc] fp32 -> BT[Nc][K] bf16
__device__ __forceinline__ void tw1(const float* B, bf16r* BT, int i, int K, int Nc) {
  int k = i / Nc, n = i - k * Nc;
  BT[(size_t)n * K + k] = f2b(B[i]);
}
__global__ void transpose_all(const float* __restrict__ b0, const float* __restrict__ b1,
                              const float* __restrict__ b2, const float* __restrict__ b3,
                              const float* __restrict__ b4, const float* __restrict__ b5,
                              bf16r* __restrict__ t0, bf16r* __restrict__ t1,
                              bf16r* __restrict__ t2, bf16r* __restrict__ t3,
                              bf16r* __restrict__ t4, bf16r* __restrict__ t5) {
  int idx = blockIdx.x * 256 + threadIdx.x;
  // cum: 65536, 196608, 327680, 491520, 688128, 737280
  if (idx < 196608) {
    if (idx < 65536) tw1(b0, t0, idx, 128, 512);
    else tw1(b1, t1, idx - 65536, 256, 512);
  } else if (idx < 491520) {
    if (idx < 327680) tw1(b2, t2, idx - 196608, 256, 512);
    else tw1(b3, t3, idx - 327680, 640, 256);
  } else if (idx < 737280) {
    if (idx < 688128) tw1(b4, t4, idx - 491520, 768, 256);
    else tw1(b5, t5, idx - 688128, 768, 64);
  }
}

// ---------------- CSR build (by dst) ----------------
__global__ void count_edges(const int* __restrict__ dst, int* __restrict__ counts) {
  int e = blockIdx.x * blockDim.x + threadIdx.x;
  if (e < NE) atomicAdd(&counts[dst[e]], 1);
}

// 2-level parallel exclusive scan over padded counts (51200 elems, 25 blocks x 2048)
__global__ __launch_bounds__(1024) void scan_local(const int* __restrict__ counts,
                                                   int* __restrict__ row_ptr,
                                                   int* __restrict__ bsum) {
  __shared__ int buf[1024];
  const int b = blockIdx.x, t = threadIdx.x;
  int2 c2 = reinterpret_cast<const int2*>(counts)[b * 1024 + t];
  int tsum = c2.x + c2.y;
  buf[t] = tsum;
  __syncthreads();
  int s = tsum;
  for (int off = 1; off < 1024; off <<= 1) {
    int add = (t >= off) ? buf[t - off] : 0;
    __syncthreads();
    s += add;
    buf[t] = s;
    __syncthreads();
  }
  int excl = s - tsum;
  int2 o;
  o.x = excl;
  o.y = excl + c2.x;
  reinterpret_cast<int2*>(row_ptr)[b * 1024 + t] = o;
  if (t == 1023) bsum[b] = s;
}

__global__ __launch_bounds__(1024) void scan_add(int* __restrict__ row_ptr,
                                                 int* __restrict__ cursor,
                                                 const int* __restrict__ bsum) {
  const int b = blockIdx.x, t = threadIdx.x;
  int off = 0;
  for (int j = 0; j < b; ++j) off += bsum[j];
  int i0 = b * 2048 + 2 * t;
#pragma unroll
  for (int k = 0; k < 2; ++k) {
    int i = i0 + k;
    if (i <= MN) {
      int v = row_ptr[i] + off;
      row_ptr[i] = v;
      if (i < MN) cursor[i] = v;
    }
  }
}

__global__ void scatter_edges(const int* __restrict__ src, const int* __restrict__ dst,
                              int* __restrict__ cursor, int* __restrict__ esrc) {
  int e = blockIdx.x * blockDim.x + threadIdx.x;
  if (e < NE) {
    int d = dst[e];
    int pos = atomicAdd(&cursor[d], 1);
    esrc[pos] = src[e];
  }
}

// ---------------- segment max, 4 feature chunks, 4-deep MLP (R12: 93.7us) -------
__global__ __launch_bounds__(256) void seg_max(const bf16r* __restrict__ h,
                                               const int* __restrict__ row_ptr,
                                               const int* __restrict__ esrc,
                                               bf16r* __restrict__ hN) {
  const int node = blockIdx.x * 4 + (threadIdx.x >> 6);
  if (node >= MN) return;
  const int lane = threadIdx.x & 63;
  const int g = lane >> 4;
  const int sl = lane & 15;
  const int colbase = blockIdx.y * 128 + sl * 8;  // feature offset (8 bf16 = 16B)
  const int beg = row_ptr[node];
  const int end = row_ptr[node + 1];
  short8 m8;
#pragma unroll
  for (int j = 0; j < 8; ++j) m8[j] = (short)0x807F;  // key(-inf bf16)

  for (int cb = beg; cb < end; cb += 16) {
    int e0 = esrc[min(cb + g, end - 1)];
    int e1 = esrc[min(cb + 4 + g, end - 1)];
    int e2 = esrc[min(cb + 8 + g, end - 1)];
    int e3 = esrc[min(cb + 12 + g, end - 1)];
    short8 u0 = *reinterpret_cast<const short8*>(h + ((size_t)e0 << 9) + colbase);
    short8 u1 = *reinterpret_cast<const short8*>(h + ((size_t)e1 << 9) + colbase);
    short8 u2 = *reinterpret_cast<const short8*>(h + ((size_t)e2 << 9) + colbase);
    short8 u3 = *reinterpret_cast<const short8*>(h + ((size_t)e3 << 9) + colbase);
    m8 = __builtin_elementwise_max(m8, __builtin_elementwise_max(
        __builtin_elementwise_max(u0, u1), __builtin_elementwise_max(u2, u3)));
  }
  // combine the 4 lane-groups (each holds max over its edge subset)
#pragma unroll
  for (int mask = 16; mask <= 32; mask <<= 1) {
    int4 vi;
    __builtin_memcpy(&vi, &m8, 16);
    int4 ot;
    ot.x = __shfl_xor(vi.x, mask);
    ot.y = __shfl_xor(vi.y, mask);
    ot.z = __shfl_xor(vi.z, mask);
    ot.w = __shfl_xor(vi.w, mask);
    short8 o8;
    __builtin_memcpy(&o8, &ot, 16);
    m8 = __builtin_elementwise_max(m8, o8);
  }
  if (lane < 16) {
    ushort8 o;
    if (beg == end) {
#pragma unroll
      for (int j = 0; j < 8; ++j) o[j] = 0;  // DGL zero-fill
    } else {
#pragma unroll
      for (int j = 0; j < 8; ++j) o[j] = keymap((unsigned short)m8[j]);
    }
    *reinterpret_cast<ushort8*>(hN + (size_t)node * PP + colbase) = o;
  }
}

// ---------------- bf16 MFMA GEMM: 3-buffer, counted-vmcnt pipeline (T4) ----------
// C[M,NC] = A1[M,K1] @ BT^T (+ A2 @ BT[][K1:]^T); optional relu.
// Each wave issues exactly 3 global_load_lds per tile-stage (ACH+BCH==3 for all
// instantiations). Pipeline: stage(0),stage(1); iter t: wait vmcnt(3) [own tile-t
// loads landed; t+1 stays in flight] -> s_barrier [all waves' tile-t in LDS] ->
// MFMA on buf t%3 -> stage(t+2) into (t+2)%3 [safe: all waves passed t-barrier =>
// finished compute(t-1), the previous reader of that buffer]. Last iter: vmcnt(0).
template <int T, int BM, int BN, int NCB, int WMC, int WNC, int K1T, int K2T,
          int NCT, bool RELU, bool KEYED, typename TO>
__global__ __launch_bounds__(T) void gemm_mfma(
    const bf16r* __restrict__ A1, const bf16r* __restrict__ A2,
    const bf16r* __restrict__ BT, TO* __restrict__ C, int M) {
  constexpr int BK = 32;
  constexpr int Ktot = K1T + K2T;
  constexpr int NT1 = K1T / BK;
  constexpr int NT = Ktot / BK;
  constexpr int WM = BM / WMC;
  constexpr int WN = BN / WNC;
  constexpr int FM = WM / 16, FN = WN / 16;
  constexpr int ACH = (BM * 64) / (T * 16);  // A staging shots
  constexpr int BCH = (BN * 64) / (T * 16);  // B staging shots
  static_assert(ACH + BCH == 3, "vmcnt(3) literal assumes 3 loads per stage");
  __shared__ short As[3][BM * BK];
  __shared__ short Bs[3][BN * BK];
  const int tid = threadIdx.x;
  const int lane = tid & 63;
  const int wv = tid >> 6;
  const int wr = wv / WNC, wc = wv % WNC;
  // bijective XCD chunk swizzle: each XCD gets a contiguous wgid range
  const int nwg = gridDim.x;
  const int q = nwg >> 3, r = nwg & 7;
  const int xcd = blockIdx.x & 7, slot = blockIdx.x >> 3;
  const int wgid = (xcd < r ? xcd * (q + 1) : r * (q + 1) + (xcd - r) * q) + slot;
  const int m0 = (wgid / NCB) * BM;
  const int n0 = (wgid % NCB) * BN;

  auto stage = [&](int t, int b) {
    const int o = tid * 16;
#pragma unroll
    for (int c = 0; c < ACH; ++c) {
      int oo = o + c * (T * 16);
      int row = oo >> 6, colb = oo & 63;
      const char* g;
      if (K2T == 0 || t < NT1)
        g = (const char*)A1 + ((size_t)(m0 + row) * K1T + t * BK) * 2 + colb;
      else
        g = (const char*)A2 + ((size_t)(m0 + row) * K2T + (t - NT1) * BK) * 2 + colb;
      async16((char*)&As[b][0] + oo, g);
    }
#pragma unroll
    for (int c = 0; c < BCH; ++c) {
      int oo = o + c * (T * 16);
      int row = oo >> 6, colb = oo & 63;
      const char* g = (const char*)BT + ((size_t)(n0 + row) * Ktot + t * BK) * 2 + colb;
      async16((char*)&Bs[b][0] + oo, g);
    }
  };

  f32x4 acc[FM][FN];
#pragma unroll
  for (int i = 0; i < FM; ++i)
#pragma unroll
    for (int j = 0; j < FN; ++j)
#pragma unroll
      for (int r2 = 0; r2 < 4; ++r2) acc[i][j][r2] = 0.f;

  stage(0, 0);
  stage(1, 1);
#pragma unroll
  for (int t = 0; t < NT; ++t) {
    if (t + 1 < NT)
      asm volatile("s_waitcnt vmcnt(3)" ::: "memory");
    else
      asm volatile("s_waitcnt vmcnt(0)" ::: "memory");
    __builtin_amdgcn_s_barrier();
    const int b = t % 3;
    short8 af[FM], bfv[FN];
#pragma unroll
    for (int i = 0; i < FM; ++i)
      af[i] = *(const short8*)(&As[b][0] + (wr * WM + i * 16 + (lane & 15)) * BK +
                               (lane >> 4) * 8);
#pragma unroll
    for (int j = 0; j < FN; ++j)
      bfv[j] = *(const short8*)(&Bs[b][0] + (wc * WN + j * 16 + (lane & 15)) * BK +
                                (lane >> 4) * 8);
#pragma unroll
    for (int i = 0; i < FM; ++i)
#pragma unroll
      for (int j = 0; j < FN; ++j)
        acc[i][j] =
            __builtin_amdgcn_mfma_f32_16x16x32_bf16(af[i], bfv[j], acc[i][j], 0, 0, 0);
    if (t + 2 < NT) stage(t + 2, (t + 2) % 3);
  }

  // epilogue: C/D layout col=lane&15, row=(lane>>4)*4+r
  const int crow0 = wr * WM + (lane >> 4) * 4;
  const int ccol0 = wc * WN + (lane & 15);
#pragma unroll
  for (int i = 0; i < FM; ++i)
#pragma unroll
    for (int j = 0; j < FN; ++j)
#pragma unroll
      for (int r2 = 0; r2 < 4; ++r2) {
        int row = m0 + crow0 + i * 16 + r2;
        if (row < M) {
          float v = acc[i][j][r2];
          if (RELU) v = fmaxf(v, 0.f);
          TO* p = &C[(size_t)row * NCT + n0 + ccol0 + j * 16];
          if (KEYED) {
            *(bf16r*)p = keymap(f2b(v));
          } else {
            stC(p, v);
          }
        }
      }
}

extern "C" void kernel_launch(void* const* d_in, const int* in_sizes, int n_in,
                              void* d_out, int out_size, void* d_ws, size_t ws_size,
                              hipStream_t stream) {
  const float* x = (const float*)d_in[0];
  const int* src = (const int*)d_in[1];
  const int* dst = (const int*)d_in[2];
  const float* aggW0 = (const float*)d_in[3];
  const float* aggW1 = (const float*)d_in[4];
  const float* aggW2 = (const float*)d_in[5];
  const float* linW0 = (const float*)d_in[6];
  const float* linW1 = (const float*)d_in[7];
  const float* linW2 = (const float*)d_in[8];
  float* out = (float*)d_out;

  char* ws = (char*)d_ws;
  size_t off = 0;
  auto alloc = [&](size_t bytes) {
    void* p = ws + off;
    off = (off + bytes + 255) & ~(size_t)255;
    return p;
  };
  // order matters: GEMM A-staging overreads last-block tail rows into the NEXT buffer
  bf16r* h = (bf16r*)alloc((size_t)MN * PP * 2);      // keyed bf16
  bf16r* hN = (bf16r*)alloc((size_t)MN * PP * 2);
  bf16r* act1 = (bf16r*)alloc((size_t)MN * HH * 2);
  bf16r* act2 = (bf16r*)alloc((size_t)MN * HH * 2);
  bf16r* xb = (bf16r*)alloc((size_t)MN * DD * 2);
  bf16r* aggW0T = (bf16r*)alloc(512 * 128 * 2);
  bf16r* aggW1T = (bf16r*)alloc(512 * 256 * 2);
  bf16r* aggW2T = (bf16r*)alloc(512 * 256 * 2);
  bf16r* linW0T = (bf16r*)alloc(640 * 256 * 2);
  bf16r* linW1T = (bf16r*)alloc(768 * 256 * 2);
  bf16r* linW2T = (bf16r*)alloc(768 * 64 * 2);
  int* row_ptr = (int*)alloc(51264 * 4);   // padded for int2 scan
  int* cursor = (int*)alloc(MN * 4);
  int* counts = (int*)alloc(51264 * 4);    // padded, zeroed
  int* bsum = (int*)alloc(32 * 4);
  int* esrc = (int*)alloc(NE * 4);

  // ---- CSR build ----
  zero_ints<<<(51264 + 255) / 256, 256, 0, stream>>>(counts, 51264);
  count_edges<<<(NE + 255) / 256, 256, 0, stream>>>(dst, counts);
  scan_local<<<25, 1024, 0, stream>>>(counts, row_ptr, bsum);
  scan_add<<<25, 1024, 0, stream>>>(row_ptr, cursor, bsum);
  scatter_edges<<<(NE + 255) / 256, 256, 0, stream>>>(src, dst, cursor, esrc);

  // ---- x -> bf16, all weight transposes ----
  conv_bf16<<<((MN * DD / 4) + 255) / 256, 256, 0, stream>>>(x, xb, MN * DD / 4);
  transpose_all<<<(737280 + 255) / 256, 256, 0, stream>>>(
      aggW0, aggW1, aggW2, linW0, linW1, linW2,
      aggW0T, aggW1T, aggW2T, linW0T, linW1T, linW2T);

  const int RB256 = (MN + 255) / 256;  // 196
  const int RB128 = (MN + 127) / 128;  // 391
  dim3 gagg(RB256 * 4);                // BM=256, BN=128, 4 col-blocks
  dim3 glin(RB256 * 2);                // BM=256, BN=128, 2 col-blocks
  dim3 gout(RB128);                    // BM=128, BN=64
  dim3 gseg((MN + 3) / 4, 4);          // 4 feature chunks, y slowest

  // ---- layer 0 ----
  gemm_mfma<512, 256, 128, 4, 4, 2, 128, 0, 512, false, true, bf16r>
      <<<gagg, 512, 0, stream>>>(xb, (const bf16r*)nullptr, aggW0T, h, MN);
  seg_max<<<gseg, 256, 0, stream>>>(h, row_ptr, esrc, hN);
  gemm_mfma<512, 256, 128, 2, 4, 2, 128, 512, 256, true, false, bf16r>
      <<<glin, 512, 0, stream>>>(xb, hN, linW0T, act1, MN);

  // ---- layer 1 ----
  gemm_mfma<512, 256, 128, 4, 4, 2, 256, 0, 512, false, true, bf16r>
      <<<gagg, 512, 0, stream>>>(act1, (const bf16r*)nullptr, aggW1T, h, MN);
  seg_max<<<gseg, 256, 0, stream>>>(h, row_ptr, esrc, hN);
  gemm_mfma<512, 256, 128, 2, 4, 2, 256, 512, 256, true, false, bf16r>
      <<<glin, 512, 0, stream>>>(act1, hN, linW1T, act2, MN);

  // ---- layer 2 (output) ----
  gemm_mfma<512, 256, 128, 4, 4, 2, 256, 0, 512, false, true, bf16r>
      <<<gagg, 512, 0, stream>>>(act2, (const bf16r*)nullptr, aggW2T, h, MN);
  seg_max<<<gseg, 256, 0, stream>>>(h, row_ptr, esrc, hN);
  gemm_mfma<256, 128, 64, 1, 4, 1, 256, 512, 64, false, false, float>
      <<<gout, 256, 0, stream>>>(act2, hN, linW2T, out, MN);
}